// Round 1
// baseline (123.628 us; speedup 1.0000x reference)
//
#include <hip/hip_runtime.h>

// TT Q-value gather:
//   vec = G0[0, idx0, :]                       (8)
//   for k in 1..6: vec = vec @ Gk[:, idxk, :]  (8) x (8x8)
//   q = vec . G7[:, idx7, 0]
//
// Layouts (row-major, fp32):
//   G0: (1, 256, 8)   -> G0[n*8 + s]
//   Gk: (8, 256, 8)   -> Gk[r*2048 + n*8 + s]   (row stride 2048 floats = 8KB)
//   G7: (8, 256, 1)   -> G7[r*256 + n]
//   states: (B, 7) int32, actions: (B,) int32

#define RR 8
#define NR 2048   // N * R

__device__ __forceinline__ void tt_stage(const float* __restrict__ G, int idx,
                                         float v[8]) {
    const float* base = G + idx * RR;
    // Load the full 8x8 matrix first (16 x float4, independent -> deep ILP),
    // then FMA. Rows are 32B-aligned (idx*8*4 bytes), stride 8KB.
    float4 m[16];
#pragma unroll
    for (int r = 0; r < 8; ++r) {
        const float4* p = (const float4*)(base + r * NR);
        m[2 * r]     = p[0];
        m[2 * r + 1] = p[1];
    }
    float nv[8] = {0.f, 0.f, 0.f, 0.f, 0.f, 0.f, 0.f, 0.f};
#pragma unroll
    for (int r = 0; r < 8; ++r) {
        float vr = v[r];
        nv[0] += vr * m[2 * r].x;
        nv[1] += vr * m[2 * r].y;
        nv[2] += vr * m[2 * r].z;
        nv[3] += vr * m[2 * r].w;
        nv[4] += vr * m[2 * r + 1].x;
        nv[5] += vr * m[2 * r + 1].y;
        nv[6] += vr * m[2 * r + 1].z;
        nv[7] += vr * m[2 * r + 1].w;
    }
#pragma unroll
    for (int s = 0; s < 8; ++s) v[s] = nv[s];
}

__global__ __launch_bounds__(256) void tt_q_kernel(
    const float* __restrict__ G0, const float* __restrict__ G1,
    const float* __restrict__ G2, const float* __restrict__ G3,
    const float* __restrict__ G4, const float* __restrict__ G5,
    const float* __restrict__ G6, const float* __restrict__ G7,
    const int* __restrict__ states, const int* __restrict__ actions,
    float* __restrict__ out, int B) {
    int b = blockIdx.x * blockDim.x + threadIdx.x;
    if (b >= B) return;

    const int* srow = states + b * 7;
    int i0 = srow[0];
    int i1 = srow[1];
    int i2 = srow[2];
    int i3 = srow[3];
    int i4 = srow[4];
    int i5 = srow[5];
    int i6 = srow[6];
    int i7 = actions[b];

    float v[8];
    {
        const float4* p = (const float4*)(G0 + i0 * RR);
        float4 a = p[0], c = p[1];
        v[0] = a.x; v[1] = a.y; v[2] = a.z; v[3] = a.w;
        v[4] = c.x; v[5] = c.y; v[6] = c.z; v[7] = c.w;
    }

    tt_stage(G1, i1, v);
    tt_stage(G2, i2, v);
    tt_stage(G3, i3, v);
    tt_stage(G4, i4, v);
    tt_stage(G5, i5, v);
    tt_stage(G6, i6, v);

    // Final: q = sum_r v[r] * G7[r*256 + i7]
    float q = 0.f;
#pragma unroll
    for (int r = 0; r < 8; ++r) q += v[r] * G7[r * 256 + i7];

    out[b] = q;
}

extern "C" void kernel_launch(void* const* d_in, const int* in_sizes, int n_in,
                              void* d_out, int out_size, void* d_ws, size_t ws_size,
                              hipStream_t stream) {
    const float* G0 = (const float*)d_in[0];
    const float* G1 = (const float*)d_in[1];
    const float* G2 = (const float*)d_in[2];
    const float* G3 = (const float*)d_in[3];
    const float* G4 = (const float*)d_in[4];
    const float* G5 = (const float*)d_in[5];
    const float* G6 = (const float*)d_in[6];
    const float* G7 = (const float*)d_in[7];
    const int* states  = (const int*)d_in[8];
    const int* actions = (const int*)d_in[9];
    float* out = (float*)d_out;

    int B = in_sizes[9];  // actions is (B,)
    dim3 block(256);
    dim3 grid((B + 255) / 256);
    hipLaunchKernelGGL(tt_q_kernel, grid, block, 0, stream,
                       G0, G1, G2, G3, G4, G5, G6, G7, states, actions, out, B);
}

// Round 2
// 113.288 us; speedup vs baseline: 1.0913x; 1.0913x over previous
//
#include <hip/hip_runtime.h>

// TT Q-gather, restructured:
//   vec = V01[s0][s1][:]              (precomputed G0*G1 fold, 2MB table in ws)
//   for k in 2..5: vec = vec @ Gk[:, sk, :]   -- Gk staged through LDS
//   q   = vec . U67[s6][a][:]         (precomputed G6*G7 fold, 2MB table in ws)
//
// Global layouts (fp32): Gk (8,256,8) -> Gk[r*2048 + n*8 + s]
// LDS layout per stage: matrix n occupies float4 slots [n*16 .. n*16+15],
//   logical chunk c = 2*r + h stored at physical slot c ^ (n & 15)
//   -> gather bank phase = 4*((c ^ (n&15)) & 7), uniform over all 32 banks.

#define NN 256
#define RR 8
#define NR 2048   // N * R

__global__ __launch_bounds__(256) void build_tables(
    const float* __restrict__ G0, const float* __restrict__ G1,
    const float* __restrict__ G6, const float* __restrict__ G7,
    float* __restrict__ V01, float* __restrict__ U67) {
    const int t = threadIdx.x;
    if (blockIdx.x < NN) {
        // V01[n0][n1][s] = sum_r G0[n0,r] * G1[r,n1,s]
        const int n0 = blockIdx.x, n1 = t;
        float a[RR];
#pragma unroll
        for (int r = 0; r < RR; ++r) a[r] = G0[n0 * RR + r];
        float acc[RR] = {0.f,0.f,0.f,0.f,0.f,0.f,0.f,0.f};
#pragma unroll
        for (int r = 0; r < RR; ++r) {
            const float4* p = (const float4*)(G1 + r * NR + n1 * RR);
            float4 x = p[0], y = p[1];
            float ar = a[r];
            acc[0] += ar * x.x; acc[1] += ar * x.y;
            acc[2] += ar * x.z; acc[3] += ar * x.w;
            acc[4] += ar * y.x; acc[5] += ar * y.y;
            acc[6] += ar * y.z; acc[7] += ar * y.w;
        }
        float4* o = (float4*)(V01 + n0 * NR + n1 * RR);
        o[0] = make_float4(acc[0], acc[1], acc[2], acc[3]);
        o[1] = make_float4(acc[4], acc[5], acc[6], acc[7]);
    } else {
        // U67[n6][n7][r] = sum_s G6[r,n6,s] * G7[s,n7]
        const int n6 = blockIdx.x - NN, n7 = t;
        float g7v[RR];
#pragma unroll
        for (int s = 0; s < RR; ++s) g7v[s] = G7[s * NN + n7];
        float u[RR];
#pragma unroll
        for (int r = 0; r < RR; ++r) {
            float acc = 0.f;
#pragma unroll
            for (int s = 0; s < RR; ++s)
                acc += G6[r * NR + n6 * RR + s] * g7v[s];
            u[r] = acc;
        }
        float4* o = (float4*)(U67 + n6 * NR + n7 * RR);
        o[0] = make_float4(u[0], u[1], u[2], u[3]);
        o[1] = make_float4(u[4], u[5], u[6], u[7]);
    }
}

__global__ __launch_bounds__(256) void tt_main(
    const float* __restrict__ G2, const float* __restrict__ G3,
    const float* __restrict__ G4, const float* __restrict__ G5,
    const float* __restrict__ V01, const float* __restrict__ U67,
    const int* __restrict__ states, const int* __restrict__ actions,
    float* __restrict__ out, int B) {
    __shared__ float4 lds[NN * 16];   // 64 KB -> 2 blocks/CU

    const int t = threadIdx.x;
    const int base = blockIdx.x * 512;

    int bb[2];
    bool act[2];
    int si[2][4];   // s2..s5
    int end6[2], end7[2];
    float v[2][8];

#pragma unroll
    for (int e = 0; e < 2; ++e) {
        int b = base + e * 256 + t;
        act[e] = (b < B);
        int bc = act[e] ? b : 0;
        const int* srow = states + bc * 7;
        int s0 = srow[0], s1 = srow[1];
        si[e][0] = srow[2]; si[e][1] = srow[3];
        si[e][2] = srow[4]; si[e][3] = srow[5];
        end6[e] = srow[6];
        end7[e] = actions[bc];
        const float4* p = (const float4*)(V01 + s0 * NR + s1 * RR);
        float4 x = p[0], y = p[1];
        v[e][0] = x.x; v[e][1] = x.y; v[e][2] = x.z; v[e][3] = x.w;
        v[e][4] = y.x; v[e][5] = y.y; v[e][6] = y.z; v[e][7] = y.w;
    }

    const float* Gs[4] = {G2, G3, G4, G5};

    for (int k = 0; k < 4; ++k) {
        const float* __restrict__ G = Gs[k];
        __syncthreads();   // prior stage's reads complete before overwrite
        // cooperative staging: 2048 rows (r,n), 8 rows per thread
#pragma unroll
        for (int i = 0; i < 8; ++i) {
            int pidx = t + (i << 8);
            int r = pidx >> 8;
            int n = pidx & 255;
            const float4* gp = (const float4*)(G + r * NR + n * RR);
            float4 x = gp[0], y = gp[1];
            int xm = n & 15;
            lds[(n << 4) + ((2 * r) ^ xm)]     = x;
            lds[(n << 4) + ((2 * r + 1) ^ xm)] = y;
        }
        __syncthreads();
        // gather + 8x8 matvec per element
#pragma unroll
        for (int e = 0; e < 2; ++e) {
            int n = si[e][k];
            const float4* mp = lds + (n << 4);
            int xm = n & 15;
            float nv[8] = {0.f,0.f,0.f,0.f,0.f,0.f,0.f,0.f};
#pragma unroll
            for (int r = 0; r < 8; ++r) {
                float4 x = mp[(2 * r) ^ xm];
                float4 y = mp[(2 * r + 1) ^ xm];
                float vr = v[e][r];
                nv[0] += vr * x.x; nv[1] += vr * x.y;
                nv[2] += vr * x.z; nv[3] += vr * x.w;
                nv[4] += vr * y.x; nv[5] += vr * y.y;
                nv[6] += vr * y.z; nv[7] += vr * y.w;
            }
#pragma unroll
            for (int s = 0; s < 8; ++s) v[e][s] = nv[s];
        }
    }

    // ends: q = vec . U67[s6][a][:]
#pragma unroll
    for (int e = 0; e < 2; ++e) {
        const float4* p = (const float4*)(U67 + end6[e] * NR + end7[e] * RR);
        float4 x = p[0], y = p[1];
        float q = v[e][0] * x.x + v[e][1] * x.y + v[e][2] * x.z + v[e][3] * x.w
                + v[e][4] * y.x + v[e][5] * y.y + v[e][6] * y.z + v[e][7] * y.w;
        int b = base + e * 256 + t;
        if (act[e]) out[b] = q;
    }
}

extern "C" void kernel_launch(void* const* d_in, const int* in_sizes, int n_in,
                              void* d_out, int out_size, void* d_ws, size_t ws_size,
                              hipStream_t stream) {
    const float* G0 = (const float*)d_in[0];
    const float* G1 = (const float*)d_in[1];
    const float* G2 = (const float*)d_in[2];
    const float* G3 = (const float*)d_in[3];
    const float* G4 = (const float*)d_in[4];
    const float* G5 = (const float*)d_in[5];
    const float* G6 = (const float*)d_in[6];
    const float* G7 = (const float*)d_in[7];
    const int* states  = (const int*)d_in[8];
    const int* actions = (const int*)d_in[9];
    float* out = (float*)d_out;
    int B = in_sizes[9];

    float* V01 = (float*)d_ws;                 // 256*256*8 floats = 2 MB
    float* U67 = V01 + NN * NN * RR;           // 2 MB

    hipLaunchKernelGGL(build_tables, dim3(2 * NN), dim3(256), 0, stream,
                       G0, G1, G6, G7, V01, U67);

    int nblocks = (B + 511) / 512;
    hipLaunchKernelGGL(tt_main, dim3(nblocks), dim3(256), 0, stream,
                       G2, G3, G4, G5, V01, U67, states, actions, out, B);
}